// Round 11
// baseline (680.307 us; speedup 1.0000x reference)
//
#include <hip/hip_runtime.h>
#include <cstdint>
#include <cstddef>

// ---- problem dims (fixed) ----
#define B_SZ 1024
#define N_SZ 128
#define DIN 256
#define HID 256
#define DOUT 256
#define KD 512   // 4*N

typedef unsigned short u16;
typedef _Float16 f16x8 __attribute__((ext_vector_type(8)));
typedef float floatx4 __attribute__((ext_vector_type(4)));
typedef unsigned short u16x8 __attribute__((ext_vector_type(8)));
typedef unsigned short u16x4 __attribute__((ext_vector_type(4)));

#define MFMA16(a,b,c) __builtin_amdgcn_mfma_f32_16x16x32_f16(a, b, c, 0, 0, 0)

__device__ __forceinline__ u16 f2h(float f) {
    _Float16 h = (_Float16)f;           // RNE
    return *(u16*)&h;
}

// raw workgroup barrier (no lgkm drain; safe when preceding LDS reads are
// already consumed by MFMAs -> compiler's own waitcnt drained them)
__device__ __forceinline__ void barx() {
    asm volatile("" ::: "memory");
    __builtin_amdgcn_s_barrier();
    asm volatile("" ::: "memory");
}
// barrier with LDS-op completion (producer side): lgkmcnt(0) then s_barrier
__device__ __forceinline__ void bar_lgkm() {
    asm volatile("s_waitcnt lgkmcnt(0)" ::: "memory");
    __builtin_amdgcn_s_barrier();
    asm volatile("" ::: "memory");
}

// ============================================================================
// LDS region map (bytes).  Total 100 KiB static.
//   XS  (0..64K)    : x fp16 [128][256] swz  -> vT fp16 [256][128] swz -> ctx
//   QS/KS (64..96K) : q,k kd-tile [128][64] swz each  -> att fp16 [128][256B]
//   RED (96..100K)  : softmax cross-wave reduce (2x512 floats)
// XOR swizzle  byte ^= (row&7)<<4  on producer and consumer (involution).
// WEIGHTS ARE NOT STAGED IN LDS: Wq_t/Wk_t/Wv_t/Wo_t total 786KB, read by all
// 256 blocks -> permanently L2/L3-resident; B-fragments (16B/lane, aligned)
// load directly global->register.  This removes the former WD region and its
// 39 staging barriers (P1 inner loop is now barrier-free; compiler
// software-pipelines the unrolled loads across MFMAs).
// Grid = 1024 (one batch per block): R5 lesson — batch-loop per block
// thrashed L3 (2.8x regression). R9 lesson — register prefetch bundles
// exceed the VGPR budget -> scratch spill. Keep register live ranges short.
// ============================================================================
#define XS_OFF  0
#define QS_OFF  65536
#define KS_OFF  81920
#define ATT_OFF 65536
#define RED_OFF 98304

__global__ __launch_bounds__(512, 2)
void fused_att(const float* __restrict__ x,   const float* __restrict__ mask,
               const u16* __restrict__ Wq_t,  const float* __restrict__ bq,
               const u16* __restrict__ Wk_t,  const float* __restrict__ bk,
               const u16* __restrict__ Wv_t,  const float* __restrict__ bv,
               const u16* __restrict__ Wo_t,  const float* __restrict__ bo,
               float* __restrict__ out,       float* __restrict__ att)
{
    __shared__ char LD[102400];

    const int tid  = threadIdx.x;
    const int wid  = tid >> 6;          // 0..7
    const int lane = tid & 63;
    const int l16  = lane & 15;
    const int quad = lane >> 4;
    const int b    = blockIdx.x;

    // wave tiling for 128x128 / 128x256 phases: 2 M-groups x 4 N-groups
    const int swm = (wid >> 2) * 64;
    const int swn = (wid & 3) * 32;
    // wave tiling for q/k kd-tile GEMM (128 x 64): 4 M x 2 N
    const int qm0 = (wid >> 1) * 32;
    const int qn0 = (wid & 1) * 32;

    // ======================= P0: x -> XS fp16 (swizzled) ====================
    // Interleaved load/convert/store: live range = 2 float4 (R9 lesson).
    {
        const float* xb = x + (size_t)b * (N_SZ * DIN);
        int row = tid >> 2;
        int c0  = (tid & 3) * 64;
        int sw  = (row & 7) << 4;
        const float* xr = xb + (size_t)row * DIN;
#pragma unroll
        for (int u = 0; u < 8; ++u) {
            int col = c0 + u * 8;
            float4 f0 = *(const float4*)(xr + col);
            float4 f1 = *(const float4*)(xr + col + 4);
            u16x8 o;
            o[0] = f2h(f0.x); o[1] = f2h(f0.y); o[2] = f2h(f0.z); o[3] = f2h(f0.w);
            o[4] = f2h(f1.x); o[5] = f2h(f1.y); o[6] = f2h(f1.z); o[7] = f2h(f1.w);
            *(u16x8*)(LD + ((row * 512 + col * 2) ^ sw)) = o;
        }
    }
    bar_lgkm();                         // x visible

    // ---- cache P1 x A-fragments in registers (kd-invariant) ----
    f16x8 xa[2][8];
#pragma unroll
    for (int i = 0; i < 2; ++i)
#pragma unroll
        for (int t = 0; t < 8; ++t) {   // t = kc*2+ks
            int r = qm0 + i * 16 + l16;
            int kofs = t * 32 + quad * 8;
            xa[i][t] = *(const f16x8*)(LD + ((r * 512 + kofs * 2) ^ ((r & 7) << 4)));
        }

    // ======================= P1: q/k kd-tiles + scores ======================
    floatx4 sacc[4][2];
#pragma unroll
    for (int i = 0; i < 4; i++)
#pragma unroll
        for (int j = 0; j < 2; j++) sacc[i][j] = floatx4{0.f, 0.f, 0.f, 0.f};

#pragma unroll 1
    for (int kd = 0; kd < 8; ++kd) {
        float bqv[2], bkv[2];
#pragma unroll
        for (int j = 0; j < 2; j++) {
            int col = kd * 64 + qn0 + j * 16 + l16;
            bqv[j] = bq[col];
            bkv[j] = bk[col];
        }
        floatx4 qa[2][2], ka[2][2];
#pragma unroll
        for (int i = 0; i < 2; i++)
#pragma unroll
            for (int j = 0; j < 2; j++) {
                qa[i][j] = floatx4{0.f, 0.f, 0.f, 0.f};
                ka[i][j] = floatx4{0.f, 0.f, 0.f, 0.f};
            }

        // weight rows for this kd block (fp16 [n][k], L2-resident)
        const u16* Wqb = Wq_t + (size_t)(kd * 64) * DIN;
        const u16* Wkb = Wk_t + (size_t)(kd * 64) * DIN;

        // barrier-free inner pipeline: B-fragments direct global->register;
        // compiler hoists loads across the unrolled iterations.
        __builtin_amdgcn_s_setprio(1);
#pragma unroll
        for (int kc = 0; kc < 4; ++kc) {
#pragma unroll
            for (int ks = 0; ks < 2; ++ks) {
                int kofs = kc * 64 + ks * 32 + quad * 8;
                f16x8 qf[2], kf[2];
#pragma unroll
                for (int j = 0; j < 2; ++j) {
                    size_t off = (size_t)(qn0 + j * 16 + l16) * DIN + kofs;
                    qf[j] = *(const f16x8*)(Wqb + off);
                    kf[j] = *(const f16x8*)(Wkb + off);
                }
#pragma unroll
                for (int i = 0; i < 2; i++)
#pragma unroll
                    for (int j = 0; j < 2; j++) {
                        qa[i][j] = MFMA16(xa[i][kc * 2 + ks], qf[j], qa[i][j]);
                        ka[i][j] = MFMA16(xa[i][kc * 2 + ks], kf[j], ka[i][j]);
                    }
            }
        }
        __builtin_amdgcn_s_setprio(0);

        // bias + relu + fp16 -> QS/KS (swizzled)
#pragma unroll
        for (int i = 0; i < 2; i++)
#pragma unroll
            for (int j = 0; j < 2; j++)
#pragma unroll
                for (int r = 0; r < 4; r++) {
                    int rw_ = qm0 + i * 16 + quad * 4 + r;
                    int cl  = qn0 + j * 16 + l16;
                    int by  = (rw_ * 128) + ((cl * 2) ^ ((rw_ & 7) << 4));
                    *(u16*)(LD + QS_OFF + by) = f2h(fmaxf(qa[i][j][r] + bqv[j], 0.f));
                    *(u16*)(LD + KS_OFF + by) = f2h(fmaxf(ka[i][j][r] + bkv[j], 0.f));
                }
        bar_lgkm();

        // scores += q_tile @ k_tile^T
        __builtin_amdgcn_s_setprio(1);
#pragma unroll
        for (int ks = 0; ks < 2; ++ks) {
            f16x8 saf[4], sbf[2];
            int kb2 = (ks * 32 + quad * 8) * 2;
#pragma unroll
            for (int i = 0; i < 4; i++) {
                int r = swm + i * 16 + l16;
                saf[i] = *(const f16x8*)(LD + QS_OFF + (r * 128) + (kb2 ^ ((r & 7) << 4)));
            }
#pragma unroll
            for (int j = 0; j < 2; j++) {
                int n = swn + j * 16 + l16;
                sbf[j] = *(const f16x8*)(LD + KS_OFF + (n * 128) + (kb2 ^ ((n & 7) << 4)));
            }
#pragma unroll
            for (int i = 0; i < 4; i++)
#pragma unroll
                for (int j = 0; j < 2; j++)
                    sacc[i][j] = MFMA16(saf[i], sbf[j], sacc[i][j]);
        }
        __builtin_amdgcn_s_setprio(0);
        // all waves' scores reads drained (consumed by MFMAs) before next
        // kd overwrites QS/KS
        barx();
    }

    // ======================= P2: mask + softmax =============================
    {
        const float* mb = mask + (size_t)b * (N_SZ * N_SZ);
        float mreg[4][4][2];
#pragma unroll
        for (int i = 0; i < 4; i++)
#pragma unroll
            for (int r = 0; r < 4; r++) {
                int row = swm + i * 16 + quad * 4 + r;
#pragma unroll
                for (int j = 0; j < 2; j++)
                    mreg[i][r][j] = mb[row * N_SZ + swn + j * 16 + l16];
            }

        float* REDm = (float*)(LD + RED_OFF);       // [4][128]
        float* REDs = REDm + 512;                   // [4][128]
        float rmax[4][4];
#pragma unroll
        for (int i = 0; i < 4; i++) {
#pragma unroll
            for (int r = 0; r < 4; r++) {
                float mx = -1e30f;
#pragma unroll
                for (int j = 0; j < 2; j++) {
                    float mval = mreg[i][r][j];
                    float val  = sacc[i][j][r] * mval - 1000.f * (1.f - mval);
                    sacc[i][j][r] = val;
                    mx = fmaxf(mx, val);
                }
#pragma unroll
                for (int s = 1; s < 16; s <<= 1) mx = fmaxf(mx, __shfl_xor(mx, s, 64));
                rmax[i][r] = mx;
            }
        }
        if (l16 == 0) {
#pragma unroll
            for (int i = 0; i < 4; i++)
#pragma unroll
                for (int r = 0; r < 4; r++)
                    REDm[(wid & 3) * 128 + swm + i * 16 + quad * 4 + r] = rmax[i][r];
        }
        bar_lgkm();
#pragma unroll
        for (int i = 0; i < 4; i++)
#pragma unroll
            for (int r = 0; r < 4; r++) {
                int row = swm + i * 16 + quad * 4 + r;
                rmax[i][r] = fmaxf(fmaxf(REDm[row], REDm[128 + row]),
                                   fmaxf(REDm[256 + row], REDm[384 + row]));
            }

        float rsum[4][4];
#pragma unroll
        for (int i = 0; i < 4; i++) {
#pragma unroll
            for (int r = 0; r < 4; r++) {
                float s = 0.f;
#pragma unroll
                for (int j = 0; j < 2; j++) {
                    float e = __expf(sacc[i][j][r] - rmax[i][r]);
                    sacc[i][j][r] = e;
                    s += e;
                }
#pragma unroll
                for (int t = 1; t < 16; t <<= 1) s += __shfl_xor(s, t, 64);
                rsum[i][r] = s;
            }
        }
        if (l16 == 0) {
#pragma unroll
            for (int i = 0; i < 4; i++)
#pragma unroll
                for (int r = 0; r < 4; r++)
                    REDs[(wid & 3) * 128 + swm + i * 16 + quad * 4 + r] = rsum[i][r];
        }
        bar_lgkm();

        float* ao = att + (size_t)b * (N_SZ * N_SZ);
#pragma unroll
        for (int i = 0; i < 4; i++) {
#pragma unroll
            for (int r = 0; r < 4; r++) {
                int row = swm + i * 16 + quad * 4 + r;
                float inv = 1.f / (REDs[row] + REDs[128 + row] +
                                   REDs[256 + row] + REDs[384 + row]);
#pragma unroll
                for (int j = 0; j < 2; j++) {
                    int col = swn + j * 16 + l16;
                    float a = sacc[i][j][r] * inv;
                    ao[row * N_SZ + col] = a;
                    int by = (row * 256) + ((col * 2) ^ ((row & 7) << 4));
                    *(u16*)(LD + ATT_OFF + by) = f2h(a);   // overwrites dead QS/KS
                }
            }
        }
        bar_lgkm();   // ATT complete
    }

    // ======================= P3: v (full width) + PV ========================
    floatx4 ctxa[4][4];
#pragma unroll
    for (int i = 0; i < 4; i++)
#pragma unroll
        for (int j = 0; j < 4; j++) ctxa[i][j] = floatx4{0.f, 0.f, 0.f, 0.f};

    {
        floatx4 va[4][4];
#pragma unroll
        for (int i = 0; i < 4; i++)
#pragma unroll
            for (int j = 0; j < 4; j++) va[i][j] = floatx4{0.f, 0.f, 0.f, 0.f};

        // v = relu(x @ Wv + bv): A from XS (x), B direct from global Wv_t.
        // No staging, no barriers inside the loop.
        __builtin_amdgcn_s_setprio(1);
#pragma unroll
        for (int kc = 0; kc < 4; ++kc) {
#pragma unroll
            for (int ks = 0; ks < 2; ++ks) {
                int kofs = kc * 64 + ks * 32 + quad * 8;
                f16x8 af[4], wf[4];
#pragma unroll
                for (int i = 0; i < 4; i++) {
                    int r = swm + i * 16 + l16;
                    af[i] = *(const f16x8*)(LD + ((r * 512 + kofs * 2) ^ ((r & 7) << 4)));
                }
#pragma unroll
                for (int jj = 0; jj < 4; jj++) {
                    int n = (jj >> 1) * 128 + swn + (jj & 1) * 16 + l16;
                    wf[jj] = *(const f16x8*)(Wv_t + (size_t)n * DIN + kofs);
                }
#pragma unroll
                for (int i = 0; i < 4; i++)
#pragma unroll
                    for (int jj = 0; jj < 4; jj++)
                        va[i][jj] = MFMA16(af[i], wf[jj], va[i][jj]);
            }
        }
        __builtin_amdgcn_s_setprio(0);
        barx();        // all x reads (consumed by MFMAs) done before vT write

        // bias + relu + transpose-write vT[h 256][m 128] over dead XS
        // packed: 4 consecutive m per thread -> one b64 write
        float bvv[4];
#pragma unroll
        for (int jj = 0; jj < 4; jj++)
            bvv[jj] = bv[(jj >> 1) * 128 + swn + (jj & 1) * 16 + l16];
#pragma unroll
        for (int i = 0; i < 4; i++)
#pragma unroll
            for (int jj = 0; jj < 4; jj++) {
                int m0 = swm + i * 16 + quad * 4;
                int h  = (jj >> 1) * 128 + swn + (jj & 1) * 16 + l16;
                u16x4 pk;
#pragma unroll
                for (int r = 0; r < 4; r++)
                    pk[r] = f2h(fmaxf(va[i][jj][r] + bvv[jj], 0.f));
                int by = (h * 256) + ((m0 * 2) ^ ((h & 7) << 4));
                *(u16x4*)(LD + by) = pk;
            }
        bar_lgkm();

        // ctx = att @ vT  (full 256-h width in one pass)
        __builtin_amdgcn_s_setprio(1);
#pragma unroll
        for (int ks = 0; ks < 4; ++ks) {
            int kb2 = (ks * 32 + quad * 8) * 2;
            f16x8 paf[4], pbf[4];
#pragma unroll
            for (int i = 0; i < 4; i++) {
                int r = swm + i * 16 + l16;
                paf[i] = *(const f16x8*)(LD + ATT_OFF + (r * 256) + (kb2 ^ ((r & 7) << 4)));
            }
#pragma unroll
            for (int jj = 0; jj < 4; jj++) {
                int h = (jj >> 1) * 128 + swn + (jj & 1) * 16 + l16;
                pbf[jj] = *(const f16x8*)(LD + (h * 256) + (kb2 ^ ((h & 7) << 4)));
            }
#pragma unroll
            for (int i = 0; i < 4; i++)
#pragma unroll
                for (int jj = 0; jj < 4; jj++)
                    ctxa[i][jj] = MFMA16(paf[i], pbf[jj], ctxa[i][jj]);
        }
        __builtin_amdgcn_s_setprio(0);
        barx();                                       // vT/att reads done
    }

    // ======================= P4: ctx -> XS; out = relu(ctx@Wo+bo) ===========
#pragma unroll
    for (int i = 0; i < 4; i++)
#pragma unroll
        for (int jj = 0; jj < 4; jj++)
#pragma unroll
            for (int r = 0; r < 4; r++) {
                int row = swm + i * 16 + quad * 4 + r;
                int col = (jj >> 1) * 128 + swn + (jj & 1) * 16 + l16;
                int by  = (row * 512) + ((col * 2) ^ ((row & 7) << 4));
                *(u16*)(LD + by) = f2h(ctxa[i][jj][r]);
            }
    bar_lgkm();

    {
        floatx4 oa[4][4];
#pragma unroll
        for (int i = 0; i < 4; i++)
#pragma unroll
            for (int j = 0; j < 4; j++) oa[i][j] = floatx4{0.f, 0.f, 0.f, 0.f};

        // out = relu(ctx @ Wo + bo): A from XS (ctx), B direct from global.
        __builtin_amdgcn_s_setprio(1);
#pragma unroll
        for (int kc = 0; kc < 4; ++kc) {
#pragma unroll
            for (int ks = 0; ks < 2; ++ks) {
                int kofs = kc * 64 + ks * 32 + quad * 8;
                f16x8 caf[4], wof[4];
#pragma unroll
                for (int i = 0; i < 4; i++) {
                    int r = swm + i * 16 + l16;
                    caf[i] = *(const f16x8*)(LD + ((r * 512 + kofs * 2) ^ ((r & 7) << 4)));
                }
#pragma unroll
                for (int jj = 0; jj < 4; jj++) {
                    int n = (jj >> 1) * 128 + swn + (jj & 1) * 16 + l16;
                    wof[jj] = *(const f16x8*)(Wo_t + (size_t)n * HID + kofs);
                }
#pragma unroll
                for (int i = 0; i < 4; i++)
#pragma unroll
                    for (int jj = 0; jj < 4; jj++)
                        oa[i][jj] = MFMA16(caf[i], wof[jj], oa[i][jj]);
            }
        }
        __builtin_amdgcn_s_setprio(0);

        float* ob = out + (size_t)b * (N_SZ * DOUT);
        float bov[4];
#pragma unroll
        for (int jj = 0; jj < 4; jj++)
            bov[jj] = bo[(jj >> 1) * 128 + swn + (jj & 1) * 16 + l16];
#pragma unroll
        for (int i = 0; i < 4; i++)
#pragma unroll
            for (int jj = 0; jj < 4; jj++)
#pragma unroll
                for (int r = 0; r < 4; r++) {
                    int row = swm + i * 16 + quad * 4 + r;
                    int col = (jj >> 1) * 128 + swn + (jj & 1) * 16 + l16;
                    ob[(size_t)row * DOUT + col] = fmaxf(oa[i][jj][r] + bov[jj], 0.f);
                }
    }
}

// ============================================================================
// prep: all four weights -> fp16 transposed [n][k], one launch
// ============================================================================
#define SQK (DIN * KD)    // 131072
#define SVO (DIN * HID)   // 65536
__global__ __launch_bounds__(256)
void wtrans_all(const float* __restrict__ Wq, const float* __restrict__ Wk,
                const float* __restrict__ Wv, const float* __restrict__ Wo,
                u16* __restrict__ Wq_t, u16* __restrict__ Wk_t,
                u16* __restrict__ Wv_t, u16* __restrict__ Wo_t)
{
    int idx = blockIdx.x * 256 + threadIdx.x;
    if (idx < SQK) {
        int k = idx / KD, n = idx % KD;
        Wq_t[(size_t)n * DIN + k] = f2h(Wq[idx]);
    } else if (idx < 2 * SQK) {
        int i = idx - SQK;
        int k = i / KD, n = i % KD;
        Wk_t[(size_t)n * DIN + k] = f2h(Wk[i]);
    } else if (idx < 2 * SQK + SVO) {
        int i = idx - 2 * SQK;
        int k = i / HID, n = i % HID;
        Wv_t[(size_t)n * DIN + k] = f2h(Wv[i]);
    } else if (idx < 2 * SQK + 2 * SVO) {
        int i = idx - 2 * SQK - SVO;
        int k = i / DOUT, n = i % DOUT;
        Wo_t[(size_t)n * HID + k] = f2h(Wo[i]);
    }
}

// ============================================================================
extern "C" void kernel_launch(void* const* d_in, const int* in_sizes, int n_in,
                              void* d_out, int out_size, void* d_ws, size_t ws_size,
                              hipStream_t stream)
{
    const float* x    = (const float*)d_in[0];
    const float* mask = (const float*)d_in[1];
    const float* Wv   = (const float*)d_in[2];
    const float* bv   = (const float*)d_in[3];
    const float* Wq   = (const float*)d_in[4];
    const float* bq   = (const float*)d_in[5];
    const float* Wk   = (const float*)d_in[6];
    const float* bk   = (const float*)d_in[7];
    const float* Wo   = (const float*)d_in[8];
    const float* bo   = (const float*)d_in[9];

    float* out = (float*)d_out;                          // [B,N,DOUT]
    float* att = out + (size_t)B_SZ * N_SZ * DOUT;       // [B,N,N]

    // ---- workspace: only fp16 transposed weights (~786 KB) ----
    char* ws = (char*)d_ws;
    u16* Wq_t = (u16*)ws;
    u16* Wk_t = Wq_t + (size_t)KD * DIN;
    u16* Wv_t = Wk_t + (size_t)KD * DIN;
    u16* Wo_t = Wv_t + (size_t)HID * DIN;

    wtrans_all<<<(2 * SQK + 2 * SVO + 255) / 256, 256, 0, stream>>>(
        Wq, Wk, Wv, Wo, Wq_t, Wk_t, Wv_t, Wo_t);

    fused_att<<<B_SZ, 512, 0, stream>>>(x, mask,
                                        Wq_t, bq, Wk_t, bk, Wv_t, bv, Wo_t, bo,
                                        out, att);

    (void)in_sizes; (void)n_in; (void)out_size; (void)ws_size;
}

// Round 12
// 466.835 us; speedup vs baseline: 1.4573x; 1.4573x over previous
//
#include <hip/hip_runtime.h>
#include <cstdint>
#include <cstddef>

// ---- problem dims (fixed) ----
#define B_SZ 1024
#define N_SZ 128
#define DIN 256
#define HID 256
#define DOUT 256
#define KD 512   // 4*N

typedef unsigned short u16;
typedef _Float16 f16x8 __attribute__((ext_vector_type(8)));
typedef float floatx4 __attribute__((ext_vector_type(4)));
typedef unsigned short u16x8 __attribute__((ext_vector_type(8)));
typedef unsigned short u16x4 __attribute__((ext_vector_type(4)));

#define MFMA16(a,b,c) __builtin_amdgcn_mfma_f32_16x16x32_f16(a, b, c, 0, 0, 0)

__device__ __forceinline__ u16 f2h(float f) {
    _Float16 h = (_Float16)f;           // RNE
    return *(u16*)&h;
}

// raw workgroup barrier (does NOT drain vmcnt -> prefetches stay in flight)
__device__ __forceinline__ void barx() {
    asm volatile("" ::: "memory");
    __builtin_amdgcn_s_barrier();
    asm volatile("" ::: "memory");
}
// barrier with LDS-op completion (producer side): lgkmcnt(0) then s_barrier
__device__ __forceinline__ void bar_lgkm() {
    asm volatile("s_waitcnt lgkmcnt(0)" ::: "memory");
    __builtin_amdgcn_s_barrier();
    asm volatile("" ::: "memory");
}

// ============================================================================
// LDS region map (bytes).  Total 128 KiB static.
//   XS  (0..64K)    : x fp16 [128][256] swz  -> vT fp16 [256][128] swz -> ctx
//   QS/KS (64..96K) : q,k kd-tile [128][64] swz each  -> att fp16 [128][256B]
//   WD  (96..128K)  : P1: weight dbuf 2x16KB (Wq 8K + Wk 8K per buf)
//                     P2: RED (4KB)   P3/P4: full-width W chunk [256][64] 32KB
// XOR swizzle  byte ^= (row&7)<<4  on producer and consumer (involution).
// Session ledger of measured lessons:
//  R5: batch-loop per block thrashed L3 -> 2.8x regression. Grid = 1024.
//  R9: register prefetch bundles (xr16[16], early mreg) -> scratch spill
//      (+150MB HBM, -30%). Keep register live ranges short.
//  R11: direct global->reg weight B-fragments (no LDS staging) -> pure
//      latency serialization (MfmaUtil 20->11.6, FETCH unchanged). The WD
//      LDS pipeline IS the prefetch decoupling; keep it.
//  R12: launch_bounds min-blocks=2 was unsatisfiable (128KB LDS > 160KB/2)
//      and only capped the register allocator at 128 VGPR. Use (512,1).
// ============================================================================
#define XS_OFF  0
#define QS_OFF  65536
#define KS_OFF  81920
#define ATT_OFF 65536
#define WD_OFF  98304
#define RED_OFF 98304

__global__ __launch_bounds__(512, 1)
void fused_att(const float* __restrict__ x,   const float* __restrict__ mask,
               const u16* __restrict__ Wq_t,  const float* __restrict__ bq,
               const u16* __restrict__ Wk_t,  const float* __restrict__ bk,
               const u16* __restrict__ Wv_t,  const float* __restrict__ bv,
               const u16* __restrict__ Wo_t,  const float* __restrict__ bo,
               float* __restrict__ out,       float* __restrict__ att)
{
    __shared__ char LD[131072];

    const int tid  = threadIdx.x;
    const int wid  = tid >> 6;          // 0..7
    const int lane = tid & 63;
    const int l16  = lane & 15;
    const int quad = lane >> 4;
    const int b    = blockIdx.x;

    // wave tiling for 128x128 / 128x256 phases: 2 M-groups x 4 N-groups
    const int swm = (wid >> 2) * 64;
    const int swn = (wid & 3) * 32;
    // wave tiling for q/k kd-tile GEMM (128 x 64): 4 M x 2 N
    const int qm0 = (wid >> 1) * 32;
    const int qn0 = (wid & 1) * 32;

    // staging geometry: each thread owns one 16B granule per 8KB plane
    const int srow  = tid >> 3;                               // 0..63
    const int sg    = tid & 7;                                // granule
    const int swz16 = (sg * 16) ^ ((srow & 7) << 4);          // swizzled col-byte

    // global source address of a P1 weight chunk (ch = kd*4+kc)
    auto waddr = [&](const u16* Wb, int ch) -> const u16x8* {
        int kdv = ch >> 2, kcv = ch & 3;
        return (const u16x8*)(Wb + ((size_t)(kdv * 64) + srow) * DIN + kcv * 64 + sg * 8);
    };
    auto stage_writeQK = [&](int buf, u16x8 q8, u16x8 k8) {
        char* base = LD + WD_OFF + buf * 16384 + srow * 128 + swz16;
        *(u16x8*)base          = q8;
        *(u16x8*)(base + 8192) = k8;
    };
    // full-width chunk [256 rows][64 cols] = 32KB (P3/P4)
    auto load256 = [&](const u16* Wb, int kc, u16x8* r4) {
#pragma unroll
        for (int p = 0; p < 4; ++p)
            r4[p] = *(const u16x8*)(Wb + (size_t)(p * 64 + srow) * DIN + kc * 64 + sg * 8);
    };
    auto stage_write256 = [&](const u16x8* r4) {
#pragma unroll
        for (int p = 0; p < 4; ++p)
            *(u16x8*)(LD + WD_OFF + (p * 64 + srow) * 128 + swz16) = r4[p];
    };

    // ---- issue prologue weight loads (chunks 0,1) before P0 ----
    u16x8 rq[2], rk[2];
    rq[0] = *waddr(Wq_t, 0); rk[0] = *waddr(Wk_t, 0);
    rq[1] = *waddr(Wq_t, 1); rk[1] = *waddr(Wk_t, 1);

    // ======================= P0: x -> XS fp16 (swizzled) ====================
    // Interleaved load/convert/store: live range = 2 float4 (R9 lesson).
    {
        const float* xb = x + (size_t)b * (N_SZ * DIN);
        int row = tid >> 2;
        int c0  = (tid & 3) * 64;
        int sw  = (row & 7) << 4;
        const float* xr = xb + (size_t)row * DIN;
#pragma unroll
        for (int u = 0; u < 8; ++u) {
            int col = c0 + u * 8;
            float4 f0 = *(const float4*)(xr + col);
            float4 f1 = *(const float4*)(xr + col + 4);
            u16x8 o;
            o[0] = f2h(f0.x); o[1] = f2h(f0.y); o[2] = f2h(f0.z); o[3] = f2h(f0.w);
            o[4] = f2h(f1.x); o[5] = f2h(f1.y); o[6] = f2h(f1.z); o[7] = f2h(f1.w);
            *(u16x8*)(LD + ((row * 512 + col * 2) ^ sw)) = o;
        }
    }
    stage_writeQK(0, rq[0], rk[0]);
    bar_lgkm();                         // x + chunk0 visible

    // ---- cache P1 x A-fragments in registers (kd-invariant) ----
    f16x8 xa[2][8];
#pragma unroll
    for (int i = 0; i < 2; ++i)
#pragma unroll
        for (int t = 0; t < 8; ++t) {   // t = kc*2+ks
            int r = qm0 + i * 16 + l16;
            int kofs = t * 32 + quad * 8;
            xa[i][t] = *(const f16x8*)(LD + ((r * 512 + kofs * 2) ^ ((r & 7) << 4)));
        }

    // ======================= P1: q/k kd-tiles + scores ======================
    floatx4 sacc[4][2];
#pragma unroll
    for (int i = 0; i < 4; i++)
#pragma unroll
        for (int j = 0; j < 2; j++) sacc[i][j] = floatx4{0.f, 0.f, 0.f, 0.f};

#pragma unroll 1
    for (int kd = 0; kd < 8; ++kd) {
        float bqv[2], bkv[2];
#pragma unroll
        for (int j = 0; j < 2; j++) {
            int col = kd * 64 + qn0 + j * 16 + l16;
            bqv[j] = bq[col];
            bkv[j] = bk[col];
        }
        floatx4 qa[2][2], ka[2][2];
#pragma unroll
        for (int i = 0; i < 2; i++)
#pragma unroll
            for (int j = 0; j < 2; j++) {
                qa[i][j] = floatx4{0.f, 0.f, 0.f, 0.f};
                ka[i][j] = floatx4{0.f, 0.f, 0.f, 0.f};
            }

#pragma unroll
        for (int kc = 0; kc < 4; ++kc) {
            const int ch  = kd * 4 + kc;     // compute chunk (in WD[par])
            const int par = kc & 1;
            // issue loads for ch+2 (consumed by ds_write next iteration)
            if (ch + 2 < 32) {
                rq[par] = *waddr(Wq_t, ch + 2);
                rk[par] = *waddr(Wk_t, ch + 2);
            }
            const char* WQ = LD + WD_OFF + par * 16384;
            const char* WK = WQ + 8192;
            __builtin_amdgcn_s_setprio(1);
#pragma unroll
            for (int ks = 0; ks < 2; ++ks) {
                f16x8 qf[2], kf[2];
#pragma unroll
                for (int j = 0; j < 2; ++j) {
                    int n  = qn0 + j * 16 + l16;
                    int by = (n * 128) + (((ks * 32 + quad * 8) * 2) ^ ((n & 7) << 4));
                    qf[j] = *(const f16x8*)(WQ + by);
                    kf[j] = *(const f16x8*)(WK + by);
                }
#pragma unroll
                for (int i = 0; i < 2; i++)
#pragma unroll
                    for (int j = 0; j < 2; j++) {
                        qa[i][j] = MFMA16(xa[i][kc * 2 + ks], qf[j], qa[i][j]);
                        ka[i][j] = MFMA16(xa[i][kc * 2 + ks], kf[j], ka[i][j]);
                    }
            }
            __builtin_amdgcn_s_setprio(0);
            // write chunk ch+1 into WD[par^1] (nobody reads it this phase)
            if (ch + 1 < 32) stage_writeQK(par ^ 1, rq[par ^ 1], rk[par ^ 1]);
            // kc=3's barrier merged into the QS/KS bar_lgkm below: that
            // lgkm(0) drains the buf0 ds_write, and any wave reaching kd+1's
            // buf1 overwrite has consumed its kc=3 reads before passing it.
            if (kc < 3) bar_lgkm();
        }

        // bias + relu + fp16 -> QS/KS (swizzled)
#pragma unroll
        for (int i = 0; i < 2; i++)
#pragma unroll
            for (int j = 0; j < 2; j++)
#pragma unroll
                for (int r = 0; r < 4; r++) {
                    int rw_ = qm0 + i * 16 + quad * 4 + r;
                    int cl  = qn0 + j * 16 + l16;
                    int by  = (rw_ * 128) + ((cl * 2) ^ ((rw_ & 7) << 4));
                    *(u16*)(LD + QS_OFF + by) = f2h(fmaxf(qa[i][j][r] + bqv[j], 0.f));
                    *(u16*)(LD + KS_OFF + by) = f2h(fmaxf(ka[i][j][r] + bkv[j], 0.f));
                }
        bar_lgkm();

        // scores += q_tile @ k_tile^T   (no trailing barrier needed:
        // next overwrite of QS/KS is >=3 barriers away)
        __builtin_amdgcn_s_setprio(1);
#pragma unroll
        for (int ks = 0; ks < 2; ++ks) {
            f16x8 saf[4], sbf[2];
            int kb2 = (ks * 32 + quad * 8) * 2;
#pragma unroll
            for (int i = 0; i < 4; i++) {
                int r = swm + i * 16 + l16;
                saf[i] = *(const f16x8*)(LD + QS_OFF + (r * 128) + (kb2 ^ ((r & 7) << 4)));
            }
#pragma unroll
            for (int j = 0; j < 2; j++) {
                int n = swn + j * 16 + l16;
                sbf[j] = *(const f16x8*)(LD + KS_OFF + (n * 128) + (kb2 ^ ((n & 7) << 4)));
            }
#pragma unroll
            for (int i = 0; i < 4; i++)
#pragma unroll
                for (int j = 0; j < 2; j++)
                    sacc[i][j] = MFMA16(saf[i], sbf[j], sacc[i][j]);
        }
        __builtin_amdgcn_s_setprio(0);
    }

    // ======================= P2: mask + softmax =============================
    u16x8 rw[4];
    load256(Wv_t, 0, rw);               // prefetch Wv chunk0 through P2
    {
        const float* mb = mask + (size_t)b * (N_SZ * N_SZ);
        float mreg[4][4][2];
#pragma unroll
        for (int i = 0; i < 4; i++)
#pragma unroll
            for (int r = 0; r < 4; r++) {
                int row = swm + i * 16 + quad * 4 + r;
#pragma unroll
                for (int j = 0; j < 2; j++)
                    mreg[i][r][j] = mb[row * N_SZ + swn + j * 16 + l16];
            }

        float* REDm = (float*)(LD + RED_OFF);       // [4][128]
        float* REDs = REDm + 512;                   // [4][128]
        float rmax[4][4];
#pragma unroll
        for (int i = 0; i < 4; i++) {
#pragma unroll
            for (int r = 0; r < 4; r++) {
                float mx = -1e30f;
#pragma unroll
                for (int j = 0; j < 2; j++) {
                    float mval = mreg[i][r][j];
                    float val  = sacc[i][j][r] * mval - 1000.f * (1.f - mval);
                    sacc[i][j][r] = val;
                    mx = fmaxf(mx, val);
                }
#pragma unroll
                for (int s = 1; s < 16; s <<= 1) mx = fmaxf(mx, __shfl_xor(mx, s, 64));
                rmax[i][r] = mx;
            }
        }
        if (l16 == 0) {
#pragma unroll
            for (int i = 0; i < 4; i++)
#pragma unroll
                for (int r = 0; r < 4; r++)
                    REDm[(wid & 3) * 128 + swm + i * 16 + quad * 4 + r] = rmax[i][r];
        }
        bar_lgkm();
#pragma unroll
        for (int i = 0; i < 4; i++)
#pragma unroll
            for (int r = 0; r < 4; r++) {
                int row = swm + i * 16 + quad * 4 + r;
                rmax[i][r] = fmaxf(fmaxf(REDm[row], REDm[128 + row]),
                                   fmaxf(REDm[256 + row], REDm[384 + row]));
            }

        float rsum[4][4];
#pragma unroll
        for (int i = 0; i < 4; i++) {
#pragma unroll
            for (int r = 0; r < 4; r++) {
                float s = 0.f;
#pragma unroll
                for (int j = 0; j < 2; j++) {
                    float e = __expf(sacc[i][j][r] - rmax[i][r]);
                    sacc[i][j][r] = e;
                    s += e;
                }
#pragma unroll
                for (int t = 1; t < 16; t <<= 1) s += __shfl_xor(s, t, 64);
                rsum[i][r] = s;
            }
        }
        if (l16 == 0) {
#pragma unroll
            for (int i = 0; i < 4; i++)
#pragma unroll
                for (int r = 0; r < 4; r++)
                    REDs[(wid & 3) * 128 + swm + i * 16 + quad * 4 + r] = rsum[i][r];
        }
        bar_lgkm();

        float* ao = att + (size_t)b * (N_SZ * N_SZ);
#pragma unroll
        for (int i = 0; i < 4; i++) {
#pragma unroll
            for (int r = 0; r < 4; r++) {
                int row = swm + i * 16 + quad * 4 + r;
                float inv = 1.f / (REDs[row] + REDs[128 + row] +
                                   REDs[256 + row] + REDs[384 + row]);
#pragma unroll
                for (int j = 0; j < 2; j++) {
                    int col = swn + j * 16 + l16;
                    float a = sacc[i][j][r] * inv;
                    ao[row * N_SZ + col] = a;
                    int by = (row * 256) + ((col * 2) ^ ((row & 7) << 4));
                    *(u16*)(LD + ATT_OFF + by) = f2h(a);   // overwrites dead QS/KS
                }
            }
        }
        bar_lgkm();   // ATT complete; RED dead -> WD free for staging
    }

    // ======================= P3: v (full width) + PV ========================
    floatx4 ctxa[4][4];
#pragma unroll
    for (int i = 0; i < 4; i++)
#pragma unroll
        for (int j = 0; j < 4; j++) ctxa[i][j] = floatx4{0.f, 0.f, 0.f, 0.f};

    {
        floatx4 va[4][4];
#pragma unroll
        for (int i = 0; i < 4; i++)
#pragma unroll
            for (int j = 0; j < 4; j++) va[i][j] = floatx4{0.f, 0.f, 0.f, 0.f};

#pragma unroll
        for (int kc = 0; kc < 4; ++kc) {
            stage_write256(rw);                       // chunk kc -> WD
            if (kc < 3) load256(Wv_t, kc + 1, rw);
            else        load256(Wo_t, 0, rw);         // prefetch P4 chunk0
            bar_lgkm();
            __builtin_amdgcn_s_setprio(1);
#pragma unroll
            for (int ks = 0; ks < 2; ++ks) {
                int kofs = kc * 64 + ks * 32 + quad * 8;
                f16x8 af[4], wf[4];
#pragma unroll
                for (int i = 0; i < 4; i++) {
                    int r = swm + i * 16 + l16;
                    af[i] = *(const f16x8*)(LD + ((r * 512 + kofs * 2) ^ ((r & 7) << 4)));
                }
#pragma unroll
                for (int jj = 0; jj < 4; jj++) {
                    int n = (jj >> 1) * 128 + swn + (jj & 1) * 16 + l16;
                    wf[jj] = *(const f16x8*)(LD + WD_OFF + (n * 128) +
                                             (((ks * 32 + quad * 8) * 2) ^ ((n & 7) << 4)));
                }
#pragma unroll
                for (int i = 0; i < 4; i++)
#pragma unroll
                    for (int jj = 0; jj < 4; jj++)
                        va[i][jj] = MFMA16(af[i], wf[jj], va[i][jj]);
            }
            __builtin_amdgcn_s_setprio(0);
            barx();                                   // all reads done before next write
        }

        // bias + relu + transpose-write vT[h 256][m 128] over dead XS
        // packed: 4 consecutive m per thread -> one b64 write
        float bvv[4];
#pragma unroll
        for (int jj = 0; jj < 4; jj++)
            bvv[jj] = bv[(jj >> 1) * 128 + swn + (jj & 1) * 16 + l16];
#pragma unroll
        for (int i = 0; i < 4; i++)
#pragma unroll
            for (int jj = 0; jj < 4; jj++) {
                int m0 = swm + i * 16 + quad * 4;
                int h  = (jj >> 1) * 128 + swn + (jj & 1) * 16 + l16;
                u16x4 pk;
#pragma unroll
                for (int r = 0; r < 4; r++)
                    pk[r] = f2h(fmaxf(va[i][jj][r] + bvv[jj], 0.f));
                int by = (h * 256) + ((m0 * 2) ^ ((h & 7) << 4));
                *(u16x4*)(LD + by) = pk;
            }
        bar_lgkm();

        // ctx = att @ vT  (full 256-h width in one pass)
        __builtin_amdgcn_s_setprio(1);
#pragma unroll
        for (int ks = 0; ks < 4; ++ks) {
            int kb2 = (ks * 32 + quad * 8) * 2;
            f16x8 paf[4], pbf[4];
#pragma unroll
            for (int i = 0; i < 4; i++) {
                int r = swm + i * 16 + l16;
                paf[i] = *(const f16x8*)(LD + ATT_OFF + (r * 256) + (kb2 ^ ((r & 7) << 4)));
            }
#pragma unroll
            for (int jj = 0; jj < 4; jj++) {
                int h = (jj >> 1) * 128 + swn + (jj & 1) * 16 + l16;
                pbf[jj] = *(const f16x8*)(LD + (h * 256) + (kb2 ^ ((h & 7) << 4)));
            }
#pragma unroll
            for (int i = 0; i < 4; i++)
#pragma unroll
                for (int jj = 0; jj < 4; jj++)
                    ctxa[i][jj] = MFMA16(paf[i], pbf[jj], ctxa[i][jj]);
        }
        __builtin_amdgcn_s_setprio(0);
        barx();                                       // vT reads done
    }

    // ======================= P4: ctx -> XS; out = relu(ctx@Wo+bo) ===========
#pragma unroll
    for (int i = 0; i < 4; i++)
#pragma unroll
        for (int jj = 0; jj < 4; jj++)
#pragma unroll
            for (int r = 0; r < 4; r++) {
                int row = swm + i * 16 + quad * 4 + r;
                int col = (jj >> 1) * 128 + swn + (jj & 1) * 16 + l16;
                int by  = (row * 512) + ((col * 2) ^ ((row & 7) << 4));
                *(u16*)(LD + by) = f2h(ctxa[i][jj][r]);
            }
    bar_lgkm();

    {
        floatx4 oa[4][4];
#pragma unroll
        for (int i = 0; i < 4; i++)
#pragma unroll
            for (int j = 0; j < 4; j++) oa[i][j] = floatx4{0.f, 0.f, 0.f, 0.f};

#pragma unroll
        for (int kc = 0; kc < 4; ++kc) {
            stage_write256(rw);                       // Wo chunk kc -> WD
            if (kc < 3) load256(Wo_t, kc + 1, rw);
            bar_lgkm();
            __builtin_amdgcn_s_setprio(1);
#pragma unroll
            for (int ks = 0; ks < 2; ++ks) {
                int kofs = kc * 64 + ks * 32 + quad * 8;
                f16x8 caf[4], wof[4];
#pragma unroll
                for (int i = 0; i < 4; i++) {
                    int r = swm + i * 16 + l16;
                    caf[i] = *(const f16x8*)(LD + ((r * 512 + kofs * 2) ^ ((r & 7) << 4)));
                }
#pragma unroll
                for (int jj = 0; jj < 4; jj++) {
                    int n = (jj >> 1) * 128 + swn + (jj & 1) * 16 + l16;
                    wof[jj] = *(const f16x8*)(LD + WD_OFF + (n * 128) +
                                              (((ks * 32 + quad * 8) * 2) ^ ((n & 7) << 4)));
                }
#pragma unroll
                for (int i = 0; i < 4; i++)
#pragma unroll
                    for (int jj = 0; jj < 4; jj++)
                        oa[i][jj] = MFMA16(caf[i], wof[jj], oa[i][jj]);
            }
            __builtin_amdgcn_s_setprio(0);
            if (kc < 3) barx();
        }

        float* ob = out + (size_t)b * (N_SZ * DOUT);
        float bov[4];
#pragma unroll
        for (int jj = 0; jj < 4; jj++)
            bov[jj] = bo[(jj >> 1) * 128 + swn + (jj & 1) * 16 + l16];
#pragma unroll
        for (int i = 0; i < 4; i++)
#pragma unroll
            for (int jj = 0; jj < 4; jj++)
#pragma unroll
                for (int r = 0; r < 4; r++) {
                    int row = swm + i * 16 + quad * 4 + r;
                    int col = (jj >> 1) * 128 + swn + (jj & 1) * 16 + l16;
                    ob[(size_t)row * DOUT + col] = fmaxf(oa[i][jj][r] + bov[jj], 0.f);
                }
    }
}

// ============================================================================
// prep: all four weights -> fp16 transposed [n][k], one launch
// ============================================================================
#define SQK (DIN * KD)    // 131072
#define SVO (DIN * HID)   // 65536
__global__ __launch_bounds__(256)
void wtrans_all(const float* __restrict__ Wq, const float* __restrict__ Wk,
                const float* __restrict__ Wv, const float* __restrict__ Wo,
                u16* __restrict__ Wq_t, u16* __restrict__ Wk_t,
                u16* __restrict__ Wv_t, u16* __restrict__ Wo_t)
{
    int idx = blockIdx.x * 256 + threadIdx.x;
    if (idx < SQK) {
        int k = idx / KD, n = idx % KD;
        Wq_t[(size_t)n * DIN + k] = f2h(Wq[idx]);
    } else if (idx < 2 * SQK) {
        int i = idx - SQK;
        int k = i / KD, n = i % KD;
        Wk_t[(size_t)n * DIN + k] = f2h(Wk[i]);
    } else if (idx < 2 * SQK + SVO) {
        int i = idx - 2 * SQK;
        int k = i / HID, n = i % HID;
        Wv_t[(size_t)n * DIN + k] = f2h(Wv[i]);
    } else if (idx < 2 * SQK + 2 * SVO) {
        int i = idx - 2 * SQK - SVO;
        int k = i / DOUT, n = i % DOUT;
        Wo_t[(size_t)n * HID + k] = f2h(Wo[i]);
    }
}

// ============================================================================
extern "C" void kernel_launch(void* const* d_in, const int* in_sizes, int n_in,
                              void* d_out, int out_size, void* d_ws, size_t ws_size,
                              hipStream_t stream)
{
    const float* x    = (const float*)d_in[0];
    const float* mask = (const float*)d_in[1];
    const float* Wv   = (const float*)d_in[2];
    const float* bv   = (const float*)d_in[3];
    const float* Wq   = (const float*)d_in[4];
    const float* bq   = (const float*)d_in[5];
    const float* Wk   = (const float*)d_in[6];
    const float* bk   = (const float*)d_in[7];
    const float* Wo   = (const float*)d_in[8];
    const float* bo   = (const float*)d_in[9];

    float* out = (float*)d_out;                          // [B,N,DOUT]
    float* att = out + (size_t)B_SZ * N_SZ * DOUT;       // [B,N,N]

    // ---- workspace: only fp16 transposed weights (~786 KB) ----
    char* ws = (char*)d_ws;
    u16* Wq_t = (u16*)ws;
    u16* Wk_t = Wq_t + (size_t)KD * DIN;
    u16* Wv_t = Wk_t + (size_t)KD * DIN;
    u16* Wo_t = Wv_t + (size_t)HID * DIN;

    wtrans_all<<<(2 * SQK + 2 * SVO + 255) / 256, 256, 0, stream>>>(
        Wq, Wk, Wv, Wo, Wq_t, Wk_t, Wv_t, Wo_t);

    fused_att<<<B_SZ, 512, 0, stream>>>(x, mask,
                                        Wq_t, bq, Wk_t, bk, Wv_t, bv, Wo_t, bo,
                                        out, att);

    (void)in_sizes; (void)n_in; (void)out_size; (void)ws_size;
}